// Round 5
// baseline (280.028 us; speedup 1.0000x reference)
//
#include <hip/hip_runtime.h>
#include <stdint.h>

#define B_    16
#define AT_   96
#define NBR_  12
#define FN_   64
#define FE_   64
#define M1    (B_*AT_*NBR_)   /* 18432 */
#define R_    (B_*AT_)        /* 1536  */
#define K1Q   128             /* layer-1 input features (bytes per row) */
#define N1    512             /* H1 */
#define K2Q   512
#define N2    128
#define SPLIT2 4

typedef _Float16 f16x8 __attribute__((ext_vector_type(8)));
typedef float    f32x4 __attribute__((ext_vector_type(4)));

/* ---- workspace layout (bytes) ---- */
#define OFF_SCAL  0u
#define OFF_B1R   256u                                  /* fp32 512  */
#define OFF_B2R   (OFF_B1R + 2048u)                     /* fp32 128  */
#define OFF_Q1    4096u                                 /* u8 M1*128 = 2.25 MB (transposed layout) */
#define OFF_W1E   (OFF_Q1  + (size_t)M1*K1Q)            /* fp16 512*1024 = 1 MB */
#define OFF_W2E   (OFF_W1E + (size_t)N1*K1Q*8*2)        /* fp16 128*4096 = 1 MB */
#define OFF_Q2    (OFF_W2E + (size_t)N2*K2Q*8*2)        /* u8 M1*512 = 9 MB (transposed layout) */
#define OFF_H     (OFF_Q2  + (size_t)M1*K2Q)            /* fp32 M1*512 = 37.75 MB */
#define OFF_ZP    OFF_H                                  /* fp16 4*M1*128 = 18.9 MB; h dead after quant_h */
#define OFF_NS    (OFF_H   + (size_t)M1*N1*4)           /* fp32 1536*64 */

__device__ __forceinline__ unsigned int enc_f(float f) {
    unsigned int u = __float_as_uint(f);
    return (u & 0x80000000u) ? ~u : (u | 0x80000000u);
}
__device__ __forceinline__ float dec_f(unsigned int u) {
    return __uint_as_float((u & 0x80000000u) ? (u & 0x7FFFFFFFu) : ~u);
}

/* init scal + zero bias accumulators (ws is poisoned 0xAA every launch) */
__global__ void k_init(unsigned int* scal, float* b1raw, float* b2raw) {
    int t = threadIdx.x;
    if (t == 0) { scal[0] = 0xFFFFFFFFu; scal[1] = 0u; scal[2] = 0xFFFFFFFFu; scal[3] = 0u; }
    if (t < N1) b1raw[t] = 0.f;
    if (t < N2) b2raw[t] = 0.f;
}

__global__ __launch_bounds__(256) void k_minmax_c1(const float* __restrict__ node,
                                                   const float* __restrict__ edge,
                                                   unsigned int* __restrict__ scal) {
    const int nn = B_*AT_*FN_;
    const int ntot = nn + M1*FE_;
    float mn = 3.0e38f, mx = -3.0e38f;
    for (int idx = blockIdx.x*blockDim.x + threadIdx.x; idx < ntot; idx += gridDim.x*blockDim.x) {
        float x = (idx < nn) ? node[idx] : edge[idx - nn];
        mn = fminf(mn, x); mx = fmaxf(mx, x);
    }
    __shared__ float smn[256], smx[256];
    smn[threadIdx.x] = mn; smx[threadIdx.x] = mx; __syncthreads();
    for (int s = 128; s > 0; s >>= 1) {
        if (threadIdx.x < s) {
            smn[threadIdx.x] = fminf(smn[threadIdx.x], smn[threadIdx.x+s]);
            smx[threadIdx.x] = fmaxf(smx[threadIdx.x], smx[threadIdx.x+s]);
        }
        __syncthreads();
    }
    if (threadIdx.x == 0) { atomicMin(&scal[0], enc_f(smn[0])); atomicMax(&scal[1], enc_f(smx[0])); }
}

/* expanded fp16 weights, o-major: We[o][k=i*8+b] = fp16( (w+0.1|w|eps_b) * 2^b * s )
   + fused bias-sum accumulation (wave-reduce, 1 atomic per wave) */
template<int KQ, int N, int SBASE, bool USE_SECOND>
__global__ __launch_bounds__(256) void k_prep_w16(const float* __restrict__ w_clean,
                                                  const float* __restrict__ eps,
                                                  const unsigned int* __restrict__ scal,
                                                  float* __restrict__ braw,
                                                  _Float16* __restrict__ We) {
    int idx = blockIdx.x*blockDim.x + threadIdx.x;   /* one thread per (o,i) */
    if (idx >= N*KQ) return;
    int o = idx / KQ;
    float mn = dec_f(scal[SBASE]), mx = dec_f(scal[SBASE+1]);
    float s = (mx - mn) * (1.0f/255.0f);
    float w = w_clean[idx];
    float aw = fabsf(w) * 0.1f;
    union { _Float16 h[8]; uint4 u; } pk;
    float p = s;
    float v7 = 0.f;
    #pragma unroll
    for (int b = 0; b < 8; b++) {
        float e = eps[(size_t)b*N*KQ + idx];
        float v = w + e*aw;
        if (b == 7) v7 = v;
        pk.h[b] = (_Float16)(v * p);
        p *= 2.0f;
    }
    *(uint4*)&We[(size_t)idx*8] = pk.u;
    /* bias-sum: wave spans 64 consecutive i of one o (KQ multiple of 64) */
    float bv = USE_SECOND ? w_clean[(size_t)N*KQ + idx] : v7;
    #pragma unroll
    for (int off = 32; off > 0; off >>= 1) bv += __shfl_down(bv, off);
    if ((threadIdx.x & 63) == 0) atomicAdd(&braw[o], bv);
}

/* quantize c1 -> q1 in kg-transposed layout:
   qt dword index = mblk*4096 + jgrp*256 + row*2 + half
   (byte layout: [mblk][jgrp=j/8][row<128][8 bytes]); one block per mblk. */
__global__ __launch_bounds__(256) void k_quant_c1(const float* __restrict__ node,
                                                  const float* __restrict__ edge,
                                                  const unsigned int* __restrict__ scal,
                                                  unsigned int* __restrict__ qt) {
    __shared__ unsigned int T[128*33];   /* padded stride 33 dwords */
    const int mblk = blockIdx.x, t = threadIdx.x;
    const float mn = dec_f(scal[0]), rng = dec_f(scal[1]) - mn;
    #pragma unroll
    for (int r = 0; r < 16; ++r) {
        int p = r*256 + t;           /* float4 index within 128x32 tile */
        int row = p >> 5, c4 = p & 31, j = c4*4;
        int m = mblk*128 + row;
        float4 x = (j < 64) ? *(const float4*)&node[(m/NBR_)*FN_ + j]
                            : *(const float4*)&edge[(size_t)m*FE_ + (j-64)];
        unsigned int b0 = (unsigned char)(int)((x.x - mn) / rng * 255.0f);
        unsigned int b1 = (unsigned char)(int)((x.y - mn) / rng * 255.0f);
        unsigned int b2 = (unsigned char)(int)((x.z - mn) / rng * 255.0f);
        unsigned int b3 = (unsigned char)(int)((x.w - mn) / rng * 255.0f);
        T[row*33 + c4] = b0 | (b1 << 8) | (b2 << 16) | (b3 << 24);
    }
    __syncthreads();
    #pragma unroll
    for (int r = 0; r < 16; ++r) {
        int o = r*256 + t;           /* jgrp=r, row=t>>1, half=t&1 */
        qt[(size_t)mblk*4096 + o] = T[(t>>1)*33 + r*2 + (t&1)];
    }
}

/* quantize h (fp32) -> q2 in kg-transposed layout; block = (mblk, jchunk of 128 cols) */
__global__ __launch_bounds__(256) void k_quant_h(const float* __restrict__ h,
                                                 const unsigned int* __restrict__ scal,
                                                 unsigned int* __restrict__ qt) {
    __shared__ unsigned int T[128*33];
    const int mblk = blockIdx.x, jc = blockIdx.y, t = threadIdx.x;
    const float mn = dec_f(scal[2]), rng = dec_f(scal[3]) - mn;
    #pragma unroll
    for (int r = 0; r < 16; ++r) {
        int p = r*256 + t;
        int row = p >> 5, c4 = p & 31;
        float4 x = *(const float4*)&h[(size_t)(mblk*128 + row)*512 + jc*128 + c4*4];
        unsigned int b0 = (unsigned char)(int)((x.x - mn) / rng * 255.0f);
        unsigned int b1 = (unsigned char)(int)((x.y - mn) / rng * 255.0f);
        unsigned int b2 = (unsigned char)(int)((x.z - mn) / rng * 255.0f);
        unsigned int b3 = (unsigned char)(int)((x.w - mn) / rng * 255.0f);
        T[row*33 + c4] = b0 | (b1 << 8) | (b2 << 16) | (b3 << 24);
    }
    __syncthreads();
    #pragma unroll
    for (int r = 0; r < 16; ++r) {
        int o = r*256 + t;
        qt[(size_t)mblk*16384 + (size_t)jc*4096 + o] = T[(t>>1)*33 + r*2 + (t&1)];
    }
}

__device__ __forceinline__ f16x8 expand_byte(unsigned int byte) {
    /* 8 bits -> 8 packed fp16 in {0.0, 1.0}; pairs via r2 = b | b<<15 */
    unsigned int r2 = byte | (byte << 15);
    union { unsigned int u[4]; f16x8 h; } t;
    t.u[0] = ( r2       & 0x00010001u) * 0x3C00u;
    t.u[1] = ((r2 >> 2) & 0x00010001u) * 0x3C00u;
    t.u[2] = ((r2 >> 4) & 0x00010001u) * 0x3C00u;
    t.u[3] = ((r2 >> 6) & 0x00010001u) * 0x3C00u;
    return t.h;
}

/* MFMA bit-plane GEMM, wave-independent form.
   1 wave per block, 64m x 64n x 1024planes per wave, 4x4 frags of 16x16x32 f16.
   NO LDS, NO barriers: B fragments read straight from L2 (W is 1 MB, fully
   L2-resident; each f16x8 load = 16 dense 64B lines), A read dense from the
   kg-transposed q layout (16 rows x 8B = 128B contiguous per load).
   Performance thesis: R0-R3 showed perf tracks independent waves/CU (barrier
   lockstep at 3-4 blocks/CU pinned MfmaUtil at ~12%); this gives 16
   independent waves/CU (launch_bounds(64,4) caps VGPR at 128). */
template<int KQ, int N, int SPLITK, bool EPI1>
__global__ __launch_bounds__(64, 4) void kgw(const unsigned char* __restrict__ q,
                                             const _Float16* __restrict__ W,
                                             const float* __restrict__ braw,
                                             void* __restrict__ outv,
                                             unsigned int* __restrict__ scal) {
    constexpr int KP  = KQ * 8;        /* total bit-planes */
    constexpr int KPS = KP / SPLITK;   /* planes per z-split (1024 both layers) */
    constexpr int NJG = KPS / 64;      /* 16: 64-plane (8-byte) groups */

    const int lane = threadIdx.x;
    const int l15 = lane & 15;
    const int lq  = lane >> 4;
    const int sh8 = lq * 8;
    const int mt  = blockIdx.x;        /* 64-row m-tile, 0..287 */
    const int o0  = blockIdx.y * 64;
    const int z   = blockIdx.z;

    f32x4 acc[4][4] = {};

    /* A: transposed layout [mblk<M1/128][16KB z-chunk][jgrp][row<128][8B] */
    const unsigned char* aq = q + (size_t)(mt >> 1)*((size_t)KQ*128)
                                + (size_t)z*16384 + ((mt & 1)*64 + l15)*8;
    /* B: o-major [o][k]; per-nf per-lane row base, k via immediate offsets */
    const _Float16* wn[4];
    #pragma unroll
    for (int nf = 0; nf < 4; ++nf)
        wn[nf] = W + (size_t)(o0 + nf*16 + l15)*KP + (size_t)z*KPS + lq*8;

    #pragma unroll 2
    for (int jg = 0; jg < NJG; ++jg) {
        uint2 qd[4];
        #pragma unroll
        for (int mf = 0; mf < 4; ++mf)
            qd[mf] = *(const uint2*)(aq + jg*1024 + mf*128);
        #pragma unroll
        for (int kf = 0; kf < 2; ++kf) {
            f16x8 bf[4];
            #pragma unroll
            for (int nf = 0; nf < 4; ++nf)
                bf[nf] = *(const f16x8*)(wn[nf] + jg*64 + kf*32);
            #pragma unroll
            for (int mf = 0; mf < 4; ++mf) {
                unsigned int byte = ((kf ? qd[mf].y : qd[mf].x) >> sh8) & 0xFFu;
                f16x8 a = expand_byte(byte);
                #pragma unroll
                for (int nf = 0; nf < 4; ++nf)
                    acc[mf][nf] = __builtin_amdgcn_mfma_f32_16x16x32_f16(a, bf[nf], acc[mf][nf], 0, 0, 0);
            }
        }
    }

    /* epilogue: C/D layout col = lane&15, row = (lane>>4)*4 + r  (m89) */
    if (EPI1) {
        float* out = (float*)outv;
        const float mn1 = dec_f(scal[0]);
        float bv[4];
        #pragma unroll
        for (int nf = 0; nf < 4; ++nf) bv[nf] = mn1 * braw[o0 + nf*16 + l15];
        float tmn = 3.0e38f, tmx = -3.0e38f;
        #pragma unroll
        for (int mf = 0; mf < 4; ++mf) {
            const int mr = mt*64 + mf*16 + lq*4;
            #pragma unroll
            for (int nf = 0; nf < 4; ++nf) {
                const int oc = o0 + nf*16 + l15;
                #pragma unroll
                for (int r = 0; r < 4; ++r) {
                    float v = acc[mf][nf][r] + bv[nf];
                    v = fmaxf(v, 0.0f);
                    tmn = fminf(tmn, v); tmx = fmaxf(tmx, v);
                    out[(size_t)(mr + r)*N + oc] = v;
                }
            }
        }
        #pragma unroll
        for (int off = 32; off > 0; off >>= 1) {
            tmn = fminf(tmn, __shfl_xor(tmn, off));
            tmx = fmaxf(tmx, __shfl_xor(tmx, off));
        }
        if (lane == 0) { atomicMin(&scal[2], enc_f(tmn)); atomicMax(&scal[3], enc_f(tmx)); }
    } else {
        _Float16* op = (_Float16*)outv + (size_t)z * ((size_t)M1 * N);
        #pragma unroll
        for (int mf = 0; mf < 4; ++mf) {
            const int mr = mt*64 + mf*16 + lq*4;
            #pragma unroll
            for (int nf = 0; nf < 4; ++nf) {
                const int oc = o0 + nf*16 + l15;
                #pragma unroll
                for (int r = 0; r < 4; ++r)
                    op[(size_t)(mr + r)*N + oc] = (_Float16)acc[mf][nf][r];
            }
        }
    }
}

/* gate/extract from fp16 split-K partials -> sigmoid*tanh*mask, sum over neighbors */
__global__ __launch_bounds__(256) void k_nbr(const _Float16* __restrict__ zp,
                                             const float* __restrict__ b2raw,
                                             const unsigned int* __restrict__ scal,
                                             const float* __restrict__ mask,
                                             float* __restrict__ ns) {
    const size_t SP = (size_t)M1 * N2;
    int tid = threadIdx.x;
    int r = blockIdx.x*4 + (tid >> 6);   /* 0..1535 */
    int f = tid & 63;
    const float mn2 = dec_f(scal[2]);
    float bg = mn2 * b2raw[f], be = mn2 * b2raw[64 + f];
    float s = 0.f;
    #pragma unroll
    for (int n = 0; n < NBR_; n++) {
        int m = r*NBR_ + n;
        size_t base = (size_t)m * N2;
        float g = bg, e = be;
        #pragma unroll
        for (int z = 0; z < SPLIT2; z++) {
            g += (float)zp[z*SP + base + f];
            e += (float)zp[z*SP + base + 64 + f];
        }
        float sig = 1.0f / (1.0f + expf(-g));
        s += sig * tanhf(e) * mask[m];
    }
    ns[r*64 + f] = s;
}

/* BatchNorm (batch stats over 1536 rows) + residual + relu; one block per feature */
__global__ __launch_bounds__(256) void k_bn(const float* __restrict__ ns,
                                            const float* __restrict__ node,
                                            const float* __restrict__ gamma,
                                            const float* __restrict__ beta,
                                            float* __restrict__ out) {
    int f = blockIdx.x;
    int tid = threadIdx.x;
    float x[6];
    float s = 0.f, ss = 0.f;
    #pragma unroll
    for (int k = 0; k < 6; k++) {
        int r = tid + k*256;
        x[k] = ns[r*64 + f];
        s += x[k]; ss += x[k]*x[k];
    }
    __shared__ float rs[256], rss[256];
    rs[tid] = s; rss[tid] = ss; __syncthreads();
    for (int st = 128; st > 0; st >>= 1) {
        if (tid < st) { rs[tid] += rs[tid+st]; rss[tid] += rss[tid+st]; }
        __syncthreads();
    }
    float mean = rs[0] / 1536.0f;
    float var  = rss[0] / 1536.0f - mean*mean;
    float denom = sqrtf(var + 1e-5f);
    float g = gamma[f], bt = beta[f];
    #pragma unroll
    for (int k = 0; k < 6; k++) {
        int r = tid + k*256;
        float v = node[r*64 + f] + ((x[k] - mean) / denom * g + bt);
        out[r*64 + f] = fmaxf(v, 0.f);
    }
}

extern "C" void kernel_launch(void* const* d_in, const int* in_sizes, int n_in,
                              void* d_out, int out_size, void* d_ws, size_t ws_size,
                              hipStream_t stream) {
    const float* node  = (const float*)d_in[0];
    const float* edge  = (const float*)d_in[1];
    const float* mask  = (const float*)d_in[2];
    const float* cond1 = (const float*)d_in[3];
    const float* cond2 = (const float*)d_in[4];
    const float* eps1  = (const float*)d_in[5];
    const float* eps2  = (const float*)d_in[6];
    const float* gamma = (const float*)d_in[7];
    const float* beta  = (const float*)d_in[8];
    float* out = (float*)d_out;
    char* ws = (char*)d_ws;

    unsigned int*  scal = (unsigned int*)(ws + OFF_SCAL);
    float* b1raw = (float*)(ws + OFF_B1R);
    float* b2raw = (float*)(ws + OFF_B2R);
    unsigned char* q1 = (unsigned char*)(ws + OFF_Q1);
    _Float16* W1e = (_Float16*)(ws + OFF_W1E);
    _Float16* W2e = (_Float16*)(ws + OFF_W2E);
    unsigned char* q2 = (unsigned char*)(ws + OFF_Q2);
    float*    h  = (float*)(ws + OFF_H);
    _Float16* zp = (_Float16*)(ws + OFF_ZP);
    float*    ns = (float*)(ws + OFF_NS);

    k_init<<<1, 1024, 0, stream>>>(scal, b1raw, b2raw);
    k_minmax_c1<<<512, 256, 0, stream>>>(node, edge, scal);
    k_prep_w16<K1Q, N1, 0, false><<<(N1*K1Q + 255)/256, 256, 0, stream>>>(cond1, eps1, scal, b1raw, W1e);
    k_quant_c1<<<M1/128, 256, 0, stream>>>(node, edge, scal, (unsigned int*)q1);
    kgw<K1Q, N1, 1, true><<<dim3(M1/64, N1/64, 1), 64, 0, stream>>>(q1, W1e, b1raw, h, scal);
    k_prep_w16<K2Q, N2, 2, true><<<(N2*K2Q + 255)/256, 256, 0, stream>>>(cond2, eps2, scal, b2raw, W2e);
    k_quant_h<<<dim3(M1/128, 4), 256, 0, stream>>>(h, scal, (unsigned int*)q2);
    kgw<K2Q, N2, SPLIT2, false><<<dim3(M1/64, N2/64, SPLIT2), 64, 0, stream>>>(q2, W2e, b2raw, zp, scal);
    k_nbr<<<R_/4, 256, 0, stream>>>(zp, b2raw, scal, mask, ns);
    k_bn<<<64, 256, 0, stream>>>(ns, node, gamma, beta, out);
}

// Round 6
// 235.837 us; speedup vs baseline: 1.1874x; 1.1874x over previous
//
#include <hip/hip_runtime.h>
#include <stdint.h>

#define B_    16
#define AT_   96
#define NBR_  12
#define FN_   64
#define FE_   64
#define M1    (B_*AT_*NBR_)   /* 18432 */
#define R_    (B_*AT_)        /* 1536  */
#define K1Q   128             /* layer-1 input features (bytes per row) */
#define N1    512             /* H1 */
#define K2Q   512
#define N2    128
#define SPLIT2 4

typedef _Float16 f16x8 __attribute__((ext_vector_type(8)));
typedef float    f32x4 __attribute__((ext_vector_type(4)));

/* ---- workspace layout (bytes) ---- */
#define OFF_SCAL  0u
#define OFF_B1R   256u                                  /* fp32 512  */
#define OFF_B2R   (OFF_B1R + 2048u)                     /* fp32 128  */
#define OFF_Q1    4096u                                 /* u8 M1*128 = 2.25 MB (transposed layout) */
#define OFF_W1E   (OFF_Q1  + (size_t)M1*K1Q)            /* fp16 512*1024 = 1 MB (k-major packed) */
#define OFF_W2E   (OFF_W1E + (size_t)N1*K1Q*8*2)        /* fp16 128*4096 = 1 MB (k-major packed) */
#define OFF_Q2    (OFF_W2E + (size_t)N2*K2Q*8*2)        /* u8 M1*512 = 9 MB (transposed layout) */
#define OFF_H     (OFF_Q2  + (size_t)M1*K2Q)            /* fp32 M1*512 = 37.75 MB */
#define OFF_ZP    OFF_H                                  /* fp16 4*M1*128 = 18.9 MB; h dead after quant_h */
#define OFF_NS    (OFF_H   + (size_t)M1*N1*4)           /* fp32 1536*64 */

__device__ __forceinline__ unsigned int enc_f(float f) {
    unsigned int u = __float_as_uint(f);
    return (u & 0x80000000u) ? ~u : (u | 0x80000000u);
}
__device__ __forceinline__ float dec_f(unsigned int u) {
    return __uint_as_float((u & 0x80000000u) ? (u & 0x7FFFFFFFu) : ~u);
}

/* init scal + zero bias accumulators (ws is poisoned 0xAA every launch) */
__global__ void k_init(unsigned int* scal, float* b1raw, float* b2raw) {
    int t = threadIdx.x;
    if (t == 0) { scal[0] = 0xFFFFFFFFu; scal[1] = 0u; scal[2] = 0xFFFFFFFFu; scal[3] = 0u; }
    if (t < N1) b1raw[t] = 0.f;
    if (t < N2) b2raw[t] = 0.f;
}

__global__ __launch_bounds__(256) void k_minmax_c1(const float* __restrict__ node,
                                                   const float* __restrict__ edge,
                                                   unsigned int* __restrict__ scal) {
    const int nn = B_*AT_*FN_;
    const int ntot = nn + M1*FE_;
    float mn = 3.0e38f, mx = -3.0e38f;
    for (int idx = blockIdx.x*blockDim.x + threadIdx.x; idx < ntot; idx += gridDim.x*blockDim.x) {
        float x = (idx < nn) ? node[idx] : edge[idx - nn];
        mn = fminf(mn, x); mx = fmaxf(mx, x);
    }
    __shared__ float smn[256], smx[256];
    smn[threadIdx.x] = mn; smx[threadIdx.x] = mx; __syncthreads();
    for (int s = 128; s > 0; s >>= 1) {
        if (threadIdx.x < s) {
            smn[threadIdx.x] = fminf(smn[threadIdx.x], smn[threadIdx.x+s]);
            smx[threadIdx.x] = fmaxf(smx[threadIdx.x], smx[threadIdx.x+s]);
        }
        __syncthreads();
    }
    if (threadIdx.x == 0) { atomicMin(&scal[0], enc_f(smn[0])); atomicMax(&scal[1], enc_f(smx[0])); }
}

/* expanded fp16 weights in k-major MFMA-frag packing:
   We[nt][st][nf][l15][lq][8h]  (o = nt*64+nf*16+l15, k = st*32+lq*8+h)
   so a wave's per-nf f16x8 B-frag load (lanes = lq*16+l15) is ONE dense
   1 KB segment -> full-rate L2.  (R5's o-major layout gave 16B/line granule
   loads = 4x L2 derate.)
   + fused bias-sum accumulation (wave-reduce, 1 atomic per wave) */
template<int KQ, int N, int SBASE, bool USE_SECOND>
__global__ __launch_bounds__(256) void k_prep_w16(const float* __restrict__ w_clean,
                                                  const float* __restrict__ eps,
                                                  const unsigned int* __restrict__ scal,
                                                  float* __restrict__ braw,
                                                  _Float16* __restrict__ We) {
    int idx = blockIdx.x*blockDim.x + threadIdx.x;   /* one thread per (o,i) */
    if (idx >= N*KQ) return;
    int o = idx / KQ;
    int i = idx % KQ;
    float mn = dec_f(scal[SBASE]), mx = dec_f(scal[SBASE+1]);
    float s = (mx - mn) * (1.0f/255.0f);
    float w = w_clean[idx];
    float aw = fabsf(w) * 0.1f;
    union { _Float16 h[8]; uint4 u; } pk;
    float p = s;
    float v7 = 0.f;
    #pragma unroll
    for (int b = 0; b < 8; b++) {
        float e = eps[(size_t)b*N*KQ + idx];
        float v = w + e*aw;
        if (b == 7) v7 = v;
        pk.h[b] = (_Float16)(v * p);
        p *= 2.0f;
    }
    {
        int nt = o >> 6, nf = (o >> 4) & 3, l15o = o & 15;
        int stg = i >> 2, lqi = i & 3;
        size_t flat = ((((size_t)nt*(KQ/4) + stg)*4 + nf)*16 + l15o)*4 + lqi;
        *(uint4*)&We[flat*8] = pk.u;
    }
    /* bias-sum: wave spans 64 consecutive i of one o (KQ multiple of 64) */
    float bv = USE_SECOND ? w_clean[(size_t)N*KQ + idx] : v7;
    #pragma unroll
    for (int off = 32; off > 0; off >>= 1) bv += __shfl_down(bv, off);
    if ((threadIdx.x & 63) == 0) atomicAdd(&braw[o], bv);
}

/* quantize c1 -> q1 in kg-transposed layout:
   qt dword index = mblk*4096 + jgrp*256 + row*2 + half
   (byte layout: [mblk][jgrp=j/8][row<128][8 bytes]); one block per mblk. */
__global__ __launch_bounds__(256) void k_quant_c1(const float* __restrict__ node,
                                                  const float* __restrict__ edge,
                                                  const unsigned int* __restrict__ scal,
                                                  unsigned int* __restrict__ qt) {
    __shared__ unsigned int T[128*33];   /* padded stride 33 dwords */
    const int mblk = blockIdx.x, t = threadIdx.x;
    const float mn = dec_f(scal[0]), rng = dec_f(scal[1]) - mn;
    #pragma unroll
    for (int r = 0; r < 16; ++r) {
        int p = r*256 + t;           /* float4 index within 128x32 tile */
        int row = p >> 5, c4 = p & 31, j = c4*4;
        int m = mblk*128 + row;
        float4 x = (j < 64) ? *(const float4*)&node[(m/NBR_)*FN_ + j]
                            : *(const float4*)&edge[(size_t)m*FE_ + (j-64)];
        unsigned int b0 = (unsigned char)(int)((x.x - mn) / rng * 255.0f);
        unsigned int b1 = (unsigned char)(int)((x.y - mn) / rng * 255.0f);
        unsigned int b2 = (unsigned char)(int)((x.z - mn) / rng * 255.0f);
        unsigned int b3 = (unsigned char)(int)((x.w - mn) / rng * 255.0f);
        T[row*33 + c4] = b0 | (b1 << 8) | (b2 << 16) | (b3 << 24);
    }
    __syncthreads();
    #pragma unroll
    for (int r = 0; r < 16; ++r) {
        int o = r*256 + t;           /* jgrp=r, row=t>>1, half=t&1 */
        qt[(size_t)mblk*4096 + o] = T[(t>>1)*33 + r*2 + (t&1)];
    }
}

/* quantize h (fp32) -> q2 in kg-transposed layout; block = (mblk, jchunk of 128 cols) */
__global__ __launch_bounds__(256) void k_quant_h(const float* __restrict__ h,
                                                 const unsigned int* __restrict__ scal,
                                                 unsigned int* __restrict__ qt) {
    __shared__ unsigned int T[128*33];
    const int mblk = blockIdx.x, jc = blockIdx.y, t = threadIdx.x;
    const float mn = dec_f(scal[2]), rng = dec_f(scal[3]) - mn;
    #pragma unroll
    for (int r = 0; r < 16; ++r) {
        int p = r*256 + t;
        int row = p >> 5, c4 = p & 31;
        float4 x = *(const float4*)&h[(size_t)(mblk*128 + row)*512 + jc*128 + c4*4];
        unsigned int b0 = (unsigned char)(int)((x.x - mn) / rng * 255.0f);
        unsigned int b1 = (unsigned char)(int)((x.y - mn) / rng * 255.0f);
        unsigned int b2 = (unsigned char)(int)((x.z - mn) / rng * 255.0f);
        unsigned int b3 = (unsigned char)(int)((x.w - mn) / rng * 255.0f);
        T[row*33 + c4] = b0 | (b1 << 8) | (b2 << 16) | (b3 << 24);
    }
    __syncthreads();
    #pragma unroll
    for (int r = 0; r < 16; ++r) {
        int o = r*256 + t;
        qt[(size_t)mblk*16384 + (size_t)jc*4096 + o] = T[(t>>1)*33 + r*2 + (t&1)];
    }
}

__device__ __forceinline__ f16x8 expand_byte(unsigned int byte) {
    /* 8 bits -> 8 packed fp16 in {0.0, 1.0}; pairs via r2 = b | b<<15 */
    unsigned int r2 = byte | (byte << 15);
    union { unsigned int u[4]; f16x8 h; } t;
    t.u[0] = ( r2       & 0x00010001u) * 0x3C00u;
    t.u[1] = ((r2 >> 2) & 0x00010001u) * 0x3C00u;
    t.u[2] = ((r2 >> 4) & 0x00010001u) * 0x3C00u;
    t.u[3] = ((r2 >> 6) & 0x00010001u) * 0x3C00u;
    return t.h;
}

/* MFMA bit-plane GEMM, wave-independent + register-double-buffered.
   1 wave per block, 64m x 64n x 1024planes, 4x4 frags of 16x16x32 f16.
   No LDS, no barriers.  Fixes vs R5 (112us, MfmaUtil 6.4%):
   (1) B loads now hit the k-major packed W layout -> each f16x8 load is one
       dense 1KB segment (16 full lines) instead of 16B/line granules;
   (2) explicit named-register double-buffer (bfA/bfB, qdA/qdB, jg-unrolled
       x2, all static indexing) issues loads one compute phase ahead --
       R5's VGPR_Count=64 proved the compiler did no pipelining on its own.
   launch_bounds(64,2): VGPR cap 256 (est ~140, no spill); grid 2304 blocks
   = 9 waves/CU all resident. */
template<int KQ, int N, int SPLITK, bool EPI1>
__global__ __launch_bounds__(64, 2) void kgw(const unsigned char* __restrict__ q,
                                             const _Float16* __restrict__ W,
                                             const float* __restrict__ braw,
                                             void* __restrict__ outv,
                                             unsigned int* __restrict__ scal) {
    constexpr int KP  = KQ * 8;        /* total bit-planes */
    constexpr int KPS = KP / SPLITK;   /* planes per z-split (1024 both layers) */
    constexpr int NJG = KPS / 64;      /* 16: 64-plane (8-byte) groups */
    constexpr int NSTT = KQ / 4;       /* total 32-plane steps in W layout */

    const int lane = threadIdx.x;
    const int l15 = lane & 15;
    const int lq  = lane >> 4;
    const int sh8 = lq * 8;
    const int mt  = blockIdx.x;        /* 64-row m-tile, 0..287 */
    const int nt  = blockIdx.y;
    const int o0  = nt * 64;
    const int z   = blockIdx.z;

    f32x4 acc[4][4] = {};

    /* A: transposed layout [mblk<M1/128][16KB z-chunk][jgrp][row<128][8B] */
    const unsigned char* aq = q + (size_t)(mt >> 1)*((size_t)KQ*128)
                                + (size_t)z*16384 + ((mt & 1)*64 + l15)*8;
    /* B: k-major packed; per-lane base, frag (st,nf) at +st*2048 + nf*512 */
    const _Float16* Wb = W + ((size_t)nt*NSTT + (size_t)z*(KPS/32))*2048 + l15*32 + lq*8;

    f16x8 bfA[4], bfB[4];
    uint2 qdA[4], qdB[4];

#define LDB(st, dst) { _Pragma("unroll") \
    for (int nf = 0; nf < 4; ++nf) dst[nf] = *(const f16x8*)(Wb + (st)*2048 + nf*512); }
#define LDA(jg, dst) { _Pragma("unroll") \
    for (int mf = 0; mf < 4; ++mf) dst[mf] = *(const uint2*)(aq + (jg)*1024 + mf*128); }
#define MM(bf, qd, kf) { _Pragma("unroll") \
    for (int mf = 0; mf < 4; ++mf) { \
        unsigned int byte = (((kf) ? qd[mf].y : qd[mf].x) >> sh8) & 0xFFu; \
        f16x8 a = expand_byte(byte); \
        _Pragma("unroll") \
        for (int nf = 0; nf < 4; ++nf) \
            acc[mf][nf] = __builtin_amdgcn_mfma_f32_16x16x32_f16(a, bf[nf], acc[mf][nf], 0, 0, 0); \
    } }

    LDA(0, qdA);
    LDB(0, bfA);
    #pragma unroll 1
    for (int jg = 0; jg < NJG; jg += 2) {
        LDB(jg*2 + 1, bfB);
        LDA(jg + 1, qdB);
        MM(bfA, qdA, 0);
        LDB(jg*2 + 2, bfA);
        MM(bfB, qdA, 1);
        LDB(jg*2 + 3, bfB);
        if (jg + 2 < NJG) LDA(jg + 2, qdA);
        MM(bfA, qdB, 0);
        if (jg + 2 < NJG) LDB(jg*2 + 4, bfA);
        MM(bfB, qdB, 1);
    }
#undef LDB
#undef LDA
#undef MM

    /* epilogue: C/D layout col = lane&15, row = (lane>>4)*4 + r  (m89) */
    if (EPI1) {
        float* out = (float*)outv;
        const float mn1 = dec_f(scal[0]);
        float bv[4];
        #pragma unroll
        for (int nf = 0; nf < 4; ++nf) bv[nf] = mn1 * braw[o0 + nf*16 + l15];
        float tmn = 3.0e38f, tmx = -3.0e38f;
        #pragma unroll
        for (int mf = 0; mf < 4; ++mf) {
            const int mr = mt*64 + mf*16 + lq*4;
            #pragma unroll
            for (int nf = 0; nf < 4; ++nf) {
                const int oc = o0 + nf*16 + l15;
                #pragma unroll
                for (int r = 0; r < 4; ++r) {
                    float v = acc[mf][nf][r] + bv[nf];
                    v = fmaxf(v, 0.0f);
                    tmn = fminf(tmn, v); tmx = fmaxf(tmx, v);
                    out[(size_t)(mr + r)*N + oc] = v;
                }
            }
        }
        #pragma unroll
        for (int off = 32; off > 0; off >>= 1) {
            tmn = fminf(tmn, __shfl_xor(tmn, off));
            tmx = fmaxf(tmx, __shfl_xor(tmx, off));
        }
        if (lane == 0) { atomicMin(&scal[2], enc_f(tmn)); atomicMax(&scal[3], enc_f(tmx)); }
    } else {
        _Float16* op = (_Float16*)outv + (size_t)z * ((size_t)M1 * N);
        #pragma unroll
        for (int mf = 0; mf < 4; ++mf) {
            const int mr = mt*64 + mf*16 + lq*4;
            #pragma unroll
            for (int nf = 0; nf < 4; ++nf) {
                const int oc = o0 + nf*16 + l15;
                #pragma unroll
                for (int r = 0; r < 4; ++r)
                    op[(size_t)(mr + r)*N + oc] = (_Float16)acc[mf][nf][r];
            }
        }
    }
}

/* gate/extract from fp16 split-K partials -> sigmoid*tanh*mask, sum over neighbors */
__global__ __launch_bounds__(256) void k_nbr(const _Float16* __restrict__ zp,
                                             const float* __restrict__ b2raw,
                                             const unsigned int* __restrict__ scal,
                                             const float* __restrict__ mask,
                                             float* __restrict__ ns) {
    const size_t SP = (size_t)M1 * N2;
    int tid = threadIdx.x;
    int r = blockIdx.x*4 + (tid >> 6);   /* 0..1535 */
    int f = tid & 63;
    const float mn2 = dec_f(scal[2]);
    float bg = mn2 * b2raw[f], be = mn2 * b2raw[64 + f];
    float s = 0.f;
    #pragma unroll
    for (int n = 0; n < NBR_; n++) {
        int m = r*NBR_ + n;
        size_t base = (size_t)m * N2;
        float g = bg, e = be;
        #pragma unroll
        for (int z = 0; z < SPLIT2; z++) {
            g += (float)zp[z*SP + base + f];
            e += (float)zp[z*SP + base + 64 + f];
        }
        float sig = 1.0f / (1.0f + expf(-g));
        s += sig * tanhf(e) * mask[m];
    }
    ns[r*64 + f] = s;
}

/* BatchNorm (batch stats over 1536 rows) + residual + relu; one block per feature */
__global__ __launch_bounds__(256) void k_bn(const float* __restrict__ ns,
                                            const float* __restrict__ node,
                                            const float* __restrict__ gamma,
                                            const float* __restrict__ beta,
                                            float* __restrict__ out) {
    int f = blockIdx.x;
    int tid = threadIdx.x;
    float x[6];
    float s = 0.f, ss = 0.f;
    #pragma unroll
    for (int k = 0; k < 6; k++) {
        int r = tid + k*256;
        x[k] = ns[r*64 + f];
        s += x[k]; ss += x[k]*x[k];
    }
    __shared__ float rs[256], rss[256];
    rs[tid] = s; rss[tid] = ss; __syncthreads();
    for (int st = 128; st > 0; st >>= 1) {
        if (tid < st) { rs[tid] += rs[tid+st]; rss[tid] += rss[tid+st]; }
        __syncthreads();
    }
    float mean = rs[0] / 1536.0f;
    float var  = rss[0] / 1536.0f - mean*mean;
    float denom = sqrtf(var + 1e-5f);
    float g = gamma[f], bt = beta[f];
    #pragma unroll
    for (int k = 0; k < 6; k++) {
        int r = tid + k*256;
        float v = node[r*64 + f] + ((x[k] - mean) / denom * g + bt);
        out[r*64 + f] = fmaxf(v, 0.f);
    }
}

extern "C" void kernel_launch(void* const* d_in, const int* in_sizes, int n_in,
                              void* d_out, int out_size, void* d_ws, size_t ws_size,
                              hipStream_t stream) {
    const float* node  = (const float*)d_in[0];
    const float* edge  = (const float*)d_in[1];
    const float* mask  = (const float*)d_in[2];
    const float* cond1 = (const float*)d_in[3];
    const float* cond2 = (const float*)d_in[4];
    const float* eps1  = (const float*)d_in[5];
    const float* eps2  = (const float*)d_in[6];
    const float* gamma = (const float*)d_in[7];
    const float* beta  = (const float*)d_in[8];
    float* out = (float*)d_out;
    char* ws = (char*)d_ws;

    unsigned int*  scal = (unsigned int*)(ws + OFF_SCAL);
    float* b1raw = (float*)(ws + OFF_B1R);
    float* b2raw = (float*)(ws + OFF_B2R);
    unsigned char* q1 = (unsigned char*)(ws + OFF_Q1);
    _Float16* W1e = (_Float16*)(ws + OFF_W1E);
    _Float16* W2e = (_Float16*)(ws + OFF_W2E);
    unsigned char* q2 = (unsigned char*)(ws + OFF_Q2);
    float*    h  = (float*)(ws + OFF_H);
    _Float16* zp = (_Float16*)(ws + OFF_ZP);
    float*    ns = (float*)(ws + OFF_NS);

    k_init<<<1, 1024, 0, stream>>>(scal, b1raw, b2raw);
    k_minmax_c1<<<512, 256, 0, stream>>>(node, edge, scal);
    k_prep_w16<K1Q, N1, 0, false><<<(N1*K1Q + 255)/256, 256, 0, stream>>>(cond1, eps1, scal, b1raw, W1e);
    k_quant_c1<<<M1/128, 256, 0, stream>>>(node, edge, scal, (unsigned int*)q1);
    kgw<K1Q, N1, 1, true><<<dim3(M1/64, N1/64, 1), 64, 0, stream>>>(q1, W1e, b1raw, h, scal);
    k_prep_w16<K2Q, N2, 2, true><<<(N2*K2Q + 255)/256, 256, 0, stream>>>(cond2, eps2, scal, b2raw, W2e);
    k_quant_h<<<dim3(M1/128, 4), 256, 0, stream>>>(h, scal, (unsigned int*)q2);
    kgw<K2Q, N2, SPLIT2, false><<<dim3(M1/64, N2/64, SPLIT2), 64, 0, stream>>>(q2, W2e, b2raw, zp, scal);
    k_nbr<<<R_/4, 256, 0, stream>>>(zp, b2raw, scal, mask, ns);
    k_bn<<<64, 256, 0, stream>>>(ns, node, gamma, beta, out);
}

// Round 7
// 212.526 us; speedup vs baseline: 1.3176x; 1.1097x over previous
//
#include <hip/hip_runtime.h>
#include <stdint.h>

#define B_    16
#define AT_   96
#define NBR_  12
#define FN_   64
#define FE_   64
#define M1    (B_*AT_*NBR_)   /* 18432 */
#define R_    (B_*AT_)        /* 1536  */
#define K1Q   128             /* layer-1 input features (bytes per row) */
#define N1    512             /* H1 */
#define K2Q   512
#define N2    128
#define SPLIT2 4

typedef _Float16 f16x8 __attribute__((ext_vector_type(8)));
typedef float    f32x4 __attribute__((ext_vector_type(4)));
typedef __attribute__((address_space(1))) const void gconst_void;
typedef __attribute__((address_space(3))) void lds_void;

/* ---- workspace layout (bytes) ---- */
#define OFF_SCAL  0u
#define OFF_B1R   256u                                  /* fp32 512  */
#define OFF_B2R   (OFF_B1R + 2048u)                     /* fp32 128  */
#define OFF_Q1    4096u                                 /* u8 M1*128 = 2.25 MB (transposed layout) */
#define OFF_W1E   (OFF_Q1  + (size_t)M1*K1Q)            /* fp16 512*1024 = 1 MB (o-major) */
#define OFF_W2E   (OFF_W1E + (size_t)N1*K1Q*8*2)        /* fp16 128*4096 = 1 MB (o-major) */
#define OFF_Q2    (OFF_W2E + (size_t)N2*K2Q*8*2)        /* u8 M1*512 = 9 MB (transposed layout) */
#define OFF_H     (OFF_Q2  + (size_t)M1*K2Q)            /* fp32 M1*512 = 37.75 MB */
#define OFF_ZP    OFF_H                                  /* fp16 4*M1*128 = 18.9 MB; h dead after quant_h */
#define OFF_NS    (OFF_H   + (size_t)M1*N1*4)           /* fp32 1536*64 */

__device__ __forceinline__ unsigned int enc_f(float f) {
    unsigned int u = __float_as_uint(f);
    return (u & 0x80000000u) ? ~u : (u | 0x80000000u);
}
__device__ __forceinline__ float dec_f(unsigned int u) {
    return __uint_as_float((u & 0x80000000u) ? (u & 0x7FFFFFFFu) : ~u);
}

/* init scal + zero bias accumulators (ws is poisoned 0xAA every launch) */
__global__ void k_init(unsigned int* scal, float* b1raw, float* b2raw) {
    int t = threadIdx.x;
    if (t == 0) { scal[0] = 0xFFFFFFFFu; scal[1] = 0u; scal[2] = 0xFFFFFFFFu; scal[3] = 0u; }
    if (t < N1) b1raw[t] = 0.f;
    if (t < N2) b2raw[t] = 0.f;
}

__global__ __launch_bounds__(256) void k_minmax_c1(const float* __restrict__ node,
                                                   const float* __restrict__ edge,
                                                   unsigned int* __restrict__ scal) {
    const int nn = B_*AT_*FN_;
    const int ntot = nn + M1*FE_;
    float mn = 3.0e38f, mx = -3.0e38f;
    for (int idx = blockIdx.x*blockDim.x + threadIdx.x; idx < ntot; idx += gridDim.x*blockDim.x) {
        float x = (idx < nn) ? node[idx] : edge[idx - nn];
        mn = fminf(mn, x); mx = fmaxf(mx, x);
    }
    __shared__ float smn[256], smx[256];
    smn[threadIdx.x] = mn; smx[threadIdx.x] = mx; __syncthreads();
    for (int s = 128; s > 0; s >>= 1) {
        if (threadIdx.x < s) {
            smn[threadIdx.x] = fminf(smn[threadIdx.x], smn[threadIdx.x+s]);
            smx[threadIdx.x] = fmaxf(smx[threadIdx.x], smx[threadIdx.x+s]);
        }
        __syncthreads();
    }
    if (threadIdx.x == 0) { atomicMin(&scal[0], enc_f(smn[0])); atomicMax(&scal[1], enc_f(smx[0])); }
}

/* expanded fp16 weights, o-major: We[o][k=i*8+b] = fp16( (w+0.1|w|eps_b) * 2^b * s )
   + fused bias-sum accumulation (wave-reduce, 1 atomic per wave) */
template<int KQ, int N, int SBASE, bool USE_SECOND>
__global__ __launch_bounds__(256) void k_prep_w16(const float* __restrict__ w_clean,
                                                  const float* __restrict__ eps,
                                                  const unsigned int* __restrict__ scal,
                                                  float* __restrict__ braw,
                                                  _Float16* __restrict__ We) {
    int idx = blockIdx.x*blockDim.x + threadIdx.x;   /* one thread per (o,i) */
    if (idx >= N*KQ) return;
    int o = idx / KQ;
    float mn = dec_f(scal[SBASE]), mx = dec_f(scal[SBASE+1]);
    float s = (mx - mn) * (1.0f/255.0f);
    float w = w_clean[idx];
    float aw = fabsf(w) * 0.1f;
    union { _Float16 h[8]; uint4 u; } pk;
    float p = s;
    float v7 = 0.f;
    #pragma unroll
    for (int b = 0; b < 8; b++) {
        float e = eps[(size_t)b*N*KQ + idx];
        float v = w + e*aw;
        if (b == 7) v7 = v;
        pk.h[b] = (_Float16)(v * p);
        p *= 2.0f;
    }
    *(uint4*)&We[(size_t)idx*8] = pk.u;
    /* bias-sum: wave spans 64 consecutive i of one o (KQ multiple of 64) */
    float bv = USE_SECOND ? w_clean[(size_t)N*KQ + idx] : v7;
    #pragma unroll
    for (int off = 32; off > 0; off >>= 1) bv += __shfl_down(bv, off);
    if ((threadIdx.x & 63) == 0) atomicAdd(&braw[o], bv);
}

/* quantize c1 -> q1 in kg-transposed layout:
   byte layout: [mblk][jgrp=j/8][row<128][8 bytes]; one block per mblk. */
__global__ __launch_bounds__(256) void k_quant_c1(const float* __restrict__ node,
                                                  const float* __restrict__ edge,
                                                  const unsigned int* __restrict__ scal,
                                                  unsigned int* __restrict__ qt) {
    __shared__ unsigned int T[128*33];   /* padded stride 33 dwords */
    const int mblk = blockIdx.x, t = threadIdx.x;
    const float mn = dec_f(scal[0]), rng = dec_f(scal[1]) - mn;
    #pragma unroll
    for (int r = 0; r < 16; ++r) {
        int p = r*256 + t;           /* float4 index within 128x32 tile */
        int row = p >> 5, c4 = p & 31, j = c4*4;
        int m = mblk*128 + row;
        float4 x = (j < 64) ? *(const float4*)&node[(m/NBR_)*FN_ + j]
                            : *(const float4*)&edge[(size_t)m*FE_ + (j-64)];
        unsigned int b0 = (unsigned char)(int)((x.x - mn) / rng * 255.0f);
        unsigned int b1 = (unsigned char)(int)((x.y - mn) / rng * 255.0f);
        unsigned int b2 = (unsigned char)(int)((x.z - mn) / rng * 255.0f);
        unsigned int b3 = (unsigned char)(int)((x.w - mn) / rng * 255.0f);
        T[row*33 + c4] = b0 | (b1 << 8) | (b2 << 16) | (b3 << 24);
    }
    __syncthreads();
    #pragma unroll
    for (int r = 0; r < 16; ++r) {
        int o = r*256 + t;           /* jgrp=r, row=t>>1, half=t&1 */
        qt[(size_t)mblk*4096 + o] = T[(t>>1)*33 + r*2 + (t&1)];
    }
}

/* quantize h (fp32) -> q2 in kg-transposed layout; block = (mblk, jchunk of 128 cols) */
__global__ __launch_bounds__(256) void k_quant_h(const float* __restrict__ h,
                                                 const unsigned int* __restrict__ scal,
                                                 unsigned int* __restrict__ qt) {
    __shared__ unsigned int T[128*33];
    const int mblk = blockIdx.x, jc = blockIdx.y, t = threadIdx.x;
    const float mn = dec_f(scal[2]), rng = dec_f(scal[3]) - mn;
    #pragma unroll
    for (int r = 0; r < 16; ++r) {
        int p = r*256 + t;
        int row = p >> 5, c4 = p & 31;
        float4 x = *(const float4*)&h[(size_t)(mblk*128 + row)*512 + jc*128 + c4*4];
        unsigned int b0 = (unsigned char)(int)((x.x - mn) / rng * 255.0f);
        unsigned int b1 = (unsigned char)(int)((x.y - mn) / rng * 255.0f);
        unsigned int b2 = (unsigned char)(int)((x.z - mn) / rng * 255.0f);
        unsigned int b3 = (unsigned char)(int)((x.w - mn) / rng * 255.0f);
        T[row*33 + c4] = b0 | (b1 << 8) | (b2 << 16) | (b3 << 24);
    }
    __syncthreads();
    #pragma unroll
    for (int r = 0; r < 16; ++r) {
        int o = r*256 + t;
        qt[(size_t)mblk*16384 + (size_t)jc*4096 + o] = T[(t>>1)*33 + r*2 + (t&1)];
    }
}

__device__ __forceinline__ f16x8 expand_byte(unsigned int byte) {
    /* 8 bits -> 8 packed fp16 in {0.0, 1.0}; pairs via r2 = b | b<<15 */
    unsigned int r2 = byte | (byte << 15);
    union { unsigned int u[4]; f16x8 h; } t;
    t.u[0] = ( r2       & 0x00010001u) * 0x3C00u;
    t.u[1] = ((r2 >> 2) & 0x00010001u) * 0x3C00u;
    t.u[2] = ((r2 >> 4) & 0x00010001u) * 0x3C00u;
    t.u[3] = ((r2 >> 6) & 0x00010001u) * 0x3C00u;
    return t.h;
}

/* MFMA bit-plane GEMM, deep-pipelined (evolves the proven R1 structure):
   - Block 256 thr / 4 waves on a 2m x 2n grid; tile 128m x 64n; each wave
     64m x 32n via 4x2 frags of 16x16x32 f16; acc = 32 VGPR.
   - BK=64 planes/iter, NIT=16: finer phases than R1's 8.
   - B triple-buffered (3 x 8KB, XOR-swizzled via pre-swizzled gl_lds source);
     counted vmcnt(4): each B tile gets ~2 compute phases to land (R1 gave 1).
   - A staged ONCE per block: dense 16KB gl_lds burst from transposed q.
   - No K-group split -> no LDS acc reduction, no tail barriers.
   - LDS 40KB -> 4 blocks/CU; launch_bounds(256,4) caps VGPR at 128.
   - XCD-chunked swizzle (1152 %% 8 == 0): each XCD keeps one (y,z) W-slice
     + q chunk L2-local. */
template<int KQ, int N, int SPLITK, bool EPI1>
__global__ __launch_bounds__(256, 4) void kgp(const unsigned char* __restrict__ q,
                                              const _Float16* __restrict__ W,
                                              const float* __restrict__ braw,
                                              void* __restrict__ outv,
                                              unsigned int* __restrict__ scal) {
    constexpr int KP  = KQ * 8;          /* total bit-planes */
    constexpr int KPS = KP / SPLITK;     /* planes per z-split (1024 both) */
    constexpr int NIT = KPS / 64;        /* 16 */
    constexpr int NT  = N / 64;
    constexpr int NMB = M1 / 128;        /* 144 m-blocks */
    constexpr int CPX = NMB * NT * SPLITK / 8;  /* 144: blocks per XCD chunk */
    __shared__ _Float16 Bs[3*4096];                   /* 24 KB B triple buffer */
    __shared__ __align__(16) unsigned char As[16384]; /* 16 KB A, whole K-chunk */

    const int tid  = threadIdx.x;
    const int lane = tid & 63;
    const int w    = tid >> 6;
    const int wm   = (w & 1) * 64;
    const int wn   = (w >> 1) * 32;
    const int l15  = lane & 15;
    const int lq   = lane >> 4;
    const int sh8  = lq * 8;

    /* XCD-chunked bijective swizzle of a 1D grid */
    const int lin = blockIdx.x;
    const int swz = (lin & 7) * CPX + (lin >> 3);
    const int x   = swz % NMB;
    const int c   = swz / NMB;
    const int y   = c % NT;
    const int z   = c / NT;
    const int m0  = x * 128;
    const int o0  = y * 64;
    const int kbase = z * KPS;

    f32x4 acc[4][2] = {};

    /* B staging geometry: slot s = iss*256+tid -> (n = sg>>3, chunk c = sg&7),
       source chunk pre-swizzled csrc = c ^ (n&7) so linear LDS write realizes
       the XOR layout (R1-verified, bank-conflict-free reads). */
    unsigned int boff[2];
    #pragma unroll
    for (int iss = 0; iss < 2; ++iss) {
        int s = iss*256 + tid, n = s >> 3, cc = s & 7;
        int csrc = cc ^ (n & 7);
        boff[iss] = (unsigned int)((o0 + n)*KP + kbase + csrc*8);
    }
    const int bdl = (tid & ~63) * 8;     /* LDS dest (halves), wave-uniform */

    auto stageB = [&](int it, int cb) {
        #pragma unroll
        for (int iss = 0; iss < 2; ++iss)
            __builtin_amdgcn_global_load_lds((gconst_void*)(W + boff[iss] + it*64),
                (lds_void*)(Bs + cb*4096 + iss*2048 + bdl), 16, 0, 0);
    };

    /* A: one dense 16 KB burst (transposed q layout: [x][z-16KB][jgrp][row][8B]) */
    const unsigned char* aq = q + (size_t)x*((size_t)KQ*128) + (size_t)z*16384;
    #pragma unroll
    for (int r = 0; r < 4; ++r)
        __builtin_amdgcn_global_load_lds((gconst_void*)(aq + r*4096 + tid*16),
            (lds_void*)(As + r*4096 + (tid & ~63)*16), 16, 0, 0);
    stageB(0, 0);
    stageB(1, 1);
    stageB(2, 2);
    asm volatile("s_waitcnt vmcnt(4)" ::: "memory");   /* A(4)+B0(2) retired */
    asm volatile("s_barrier" ::: "memory");

    auto compute = [&](int cb, int it) {
        const _Float16* Bc = Bs + cb*4096;
        uint2 qd[4];
        #pragma unroll
        for (int mf = 0; mf < 4; ++mf)
            qd[mf] = *(const uint2*)&As[it*1024 + (wm + mf*16 + l15)*8];
        #pragma unroll
        for (int kf = 0; kf < 2; ++kf) {
            f16x8 bf[2];
            #pragma unroll
            for (int nf = 0; nf < 2; ++nf) {
                const int nl = wn + nf*16 + l15;
                const int ch = kf*4 + lq;
                bf[nf] = *(const f16x8*)&Bc[nl*64 + ((ch ^ (nl & 7)) << 3)];
            }
            __builtin_amdgcn_s_setprio(1);
            #pragma unroll
            for (int mf = 0; mf < 4; ++mf) {
                unsigned int byte = ((kf ? qd[mf].y : qd[mf].x) >> sh8) & 0xFFu;
                f16x8 a = expand_byte(byte);
                #pragma unroll
                for (int nf = 0; nf < 2; ++nf)
                    acc[mf][nf] = __builtin_amdgcn_mfma_f32_16x16x32_f16(a, bf[nf], acc[mf][nf], 0, 0, 0);
            }
            __builtin_amdgcn_s_setprio(0);
        }
    };

    int cb = 0;
    #pragma unroll 1
    for (int it = 0; it < NIT-3; ++it) {
        compute(cb, it);
        asm volatile("s_waitcnt lgkmcnt(0)" ::: "memory");
        asm volatile("s_barrier" ::: "memory");       /* all waves done with buf cb */
        stageB(it+3, cb);                              /* overwrite just-consumed buf */
        asm volatile("s_waitcnt vmcnt(4)" ::: "memory"); /* B(it+1) retired; 2 tiles in flight */
        asm volatile("s_barrier" ::: "memory");
        cb = (cb == 2) ? 0 : cb + 1;
    }
    compute(cb, NIT-3);
    asm volatile("s_waitcnt lgkmcnt(0)" ::: "memory");
    asm volatile("s_barrier" ::: "memory");
    asm volatile("s_waitcnt vmcnt(2)" ::: "memory");
    asm volatile("s_barrier" ::: "memory");
    cb = (cb == 2) ? 0 : cb + 1;
    compute(cb, NIT-2);
    asm volatile("s_waitcnt lgkmcnt(0)" ::: "memory");
    asm volatile("s_barrier" ::: "memory");
    asm volatile("s_waitcnt vmcnt(0)" ::: "memory");
    asm volatile("s_barrier" ::: "memory");
    cb = (cb == 2) ? 0 : cb + 1;
    compute(cb, NIT-1);

    /* epilogue: C/D layout col = lane&15, row = (lane>>4)*4 + r  (m89) */
    if (EPI1) {
        float* out = (float*)outv;
        const float mn1 = dec_f(scal[0]);
        float bv[2];
        #pragma unroll
        for (int nf = 0; nf < 2; ++nf) bv[nf] = mn1 * braw[o0 + wn + nf*16 + l15];
        float tmn = 3.0e38f, tmx = -3.0e38f;
        #pragma unroll
        for (int mf = 0; mf < 4; ++mf) {
            const int mr = m0 + wm + mf*16 + lq*4;
            #pragma unroll
            for (int nf = 0; nf < 2; ++nf) {
                const int oc = o0 + wn + nf*16 + l15;
                #pragma unroll
                for (int r = 0; r < 4; ++r) {
                    float v = acc[mf][nf][r] + bv[nf];
                    v = fmaxf(v, 0.0f);
                    tmn = fminf(tmn, v); tmx = fmaxf(tmx, v);
                    out[(size_t)(mr + r)*N + oc] = v;
                }
            }
        }
        /* block min/max reduce via Bs scratch (free after K-loop) -> 1 atomic pair */
        __syncthreads();
        float* red = (float*)Bs;
        red[tid] = tmn; red[256 + tid] = tmx;
        __syncthreads();
        for (int s = 128; s > 0; s >>= 1) {
            if (tid < s) {
                red[tid]       = fminf(red[tid],       red[tid + s]);
                red[256 + tid] = fmaxf(red[256 + tid], red[256 + tid + s]);
            }
            __syncthreads();
        }
        if (tid == 0) { atomicMin(&scal[2], enc_f(red[0])); atomicMax(&scal[3], enc_f(red[256])); }
    } else {
        _Float16* op = (_Float16*)outv + (size_t)z * ((size_t)M1 * N);
        #pragma unroll
        for (int mf = 0; mf < 4; ++mf) {
            const int mr = m0 + wm + mf*16 + lq*4;
            #pragma unroll
            for (int nf = 0; nf < 2; ++nf) {
                const int oc = o0 + wn + nf*16 + l15;
                #pragma unroll
                for (int r = 0; r < 4; ++r)
                    op[(size_t)(mr + r)*N + oc] = (_Float16)acc[mf][nf][r];
            }
        }
    }
}

/* gate/extract from fp16 split-K partials -> sigmoid*tanh*mask, sum over neighbors */
__global__ __launch_bounds__(256) void k_nbr(const _Float16* __restrict__ zp,
                                             const float* __restrict__ b2raw,
                                             const unsigned int* __restrict__ scal,
                                             const float* __restrict__ mask,
                                             float* __restrict__ ns) {
    const size_t SP = (size_t)M1 * N2;
    int tid = threadIdx.x;
    int r = blockIdx.x*4 + (tid >> 6);   /* 0..1535 */
    int f = tid & 63;
    const float mn2 = dec_f(scal[2]);
    float bg = mn2 * b2raw[f], be = mn2 * b2raw[64 + f];
    float s = 0.f;
    #pragma unroll
    for (int n = 0; n < NBR_; n++) {
        int m = r*NBR_ + n;
        size_t base = (size_t)m * N2;
        float g = bg, e = be;
        #pragma unroll
        for (int z = 0; z < SPLIT2; z++) {
            g += (float)zp[z*SP + base + f];
            e += (float)zp[z*SP + base + 64 + f];
        }
        float sig = 1.0f / (1.0f + expf(-g));
        s += sig * tanhf(e) * mask[m];
    }
    ns[r*64 + f] = s;
}

/* BatchNorm (batch stats over 1536 rows) + residual + relu; one block per feature */
__global__ __launch_bounds__(256) void k_bn(const float* __restrict__ ns,
                                            const float* __restrict__ node,
                                            const float* __restrict__ gamma,
                                            const float* __restrict__ beta,
                                            float* __restrict__ out) {
    int f = blockIdx.x;
    int tid = threadIdx.x;
    float x[6];
    float s = 0.f, ss = 0.f;
    #pragma unroll
    for (int k = 0; k < 6; k++) {
        int r = tid + k*256;
        x[k] = ns[r*64 + f];
        s += x[k]; ss += x[k]*x[k];
    }
    __shared__ float rs[256], rss[256];
    rs[tid] = s; rss[tid] = ss; __syncthreads();
    for (int st = 128; st > 0; st >>= 1) {
        if (tid < st) { rs[tid] += rs[tid+st]; rss[tid] += rss[tid+st]; }
        __syncthreads();
    }
    float mean = rs[0] / 1536.0f;
    float var  = rss[0] / 1536.0f - mean*mean;
    float denom = sqrtf(var + 1e-5f);
    float g = gamma[f], bt = beta[f];
    #pragma unroll
    for (int k = 0; k < 6; k++) {
        int r = tid + k*256;
        float v = node[r*64 + f] + ((x[k] - mean) / denom * g + bt);
        out[r*64 + f] = fmaxf(v, 0.f);
    }
}

extern "C" void kernel_launch(void* const* d_in, const int* in_sizes, int n_in,
                              void* d_out, int out_size, void* d_ws, size_t ws_size,
                              hipStream_t stream) {
    const float* node  = (const float*)d_in[0];
    const float* edge  = (const float*)d_in[1];
    const float* mask  = (const float*)d_in[2];
    const float* cond1 = (const float*)d_in[3];
    const float* cond2 = (const float*)d_in[4];
    const float* eps1  = (const float*)d_in[5];
    const float* eps2  = (const float*)d_in[6];
    const float* gamma = (const float*)d_in[7];
    const float* beta  = (const float*)d_in[8];
    float* out = (float*)d_out;
    char* ws = (char*)d_ws;

    unsigned int*  scal = (unsigned int*)(ws + OFF_SCAL);
    float* b1raw = (float*)(ws + OFF_B1R);
    float* b2raw = (float*)(ws + OFF_B2R);
    unsigned char* q1 = (unsigned char*)(ws + OFF_Q1);
    _Float16* W1e = (_Float16*)(ws + OFF_W1E);
    _Float16* W2e = (_Float16*)(ws + OFF_W2E);
    unsigned char* q2 = (unsigned char*)(ws + OFF_Q2);
    float*    h  = (float*)(ws + OFF_H);
    _Float16* zp = (_Float16*)(ws + OFF_ZP);
    float*    ns = (float*)(ws + OFF_NS);

    k_init<<<1, 1024, 0, stream>>>(scal, b1raw, b2raw);
    k_minmax_c1<<<512, 256, 0, stream>>>(node, edge, scal);
    k_prep_w16<K1Q, N1, 0, false><<<(N1*K1Q + 255)/256, 256, 0, stream>>>(cond1, eps1, scal, b1raw, W1e);
    k_quant_c1<<<M1/128, 256, 0, stream>>>(node, edge, scal, (unsigned int*)q1);
    kgp<K1Q, N1, 1, true><<<(M1/128)*(N1/64), 256, 0, stream>>>(q1, W1e, b1raw, h, scal);
    k_prep_w16<K2Q, N2, 2, true><<<(N2*K2Q + 255)/256, 256, 0, stream>>>(cond2, eps2, scal, b2raw, W2e);
    k_quant_h<<<dim3(M1/128, 4), 256, 0, stream>>>(h, scal, (unsigned int*)q2);
    kgp<K2Q, N2, SPLIT2, false><<<(M1/128)*(N2/64)*SPLIT2, 256, 0, stream>>>(q2, W2e, b2raw, zp, scal);
    k_nbr<<<R_/4, 256, 0, stream>>>(zp, b2raw, scal, mask, ns);
    k_bn<<<64, 256, 0, stream>>>(ns, node, gamma, beta, out);
}